// Round 8
// baseline (252.267 us; speedup 1.0000x reference)
//
#include <hip/hip_runtime.h>
#include <climits>

// StreamingRhythmProjector: B=4096 rows x U=2048 units.
// R8: PRODUCER/CONSUMER SPLIT. Evidence: harness fillBuffer hits 6.6 TB/s in
// the same capture while every fused variant (R2-R7) pins at 2.1-2.4 TB/s ->
// the pin is the mixed read+reduce+write structure. Kernel A (one wave/row,
// reads only) computes visible/commit/scales/scalars into d_ws + d_out.
// Kernel B is fill-shaped: no barriers/shuffles, scalar params, predicated
// L3-hot reads, 3 NT float4 stores; zero-tail is pure zero-fill.

constexpr int UNITS = 2048;

typedef float f32x4 __attribute__((ext_vector_type(4)));

static __device__ __forceinline__ float bflySum(float v) {
#pragma unroll
  for (int m = 1; m < 64; m <<= 1) v += __shfl_xor(v, m, 64);
  return v;  // all lanes hold the sum
}

// ---------------- Kernel A: per-row stats (reads only) ----------------
__global__ __launch_bounds__(256, 4) void stats_kernel(
    const float* __restrict__ dur_anchor,    // [B,U]
    const float* __restrict__ unit_mask,     // [B,U] prefix mask
    const float* __restrict__ speech_budget, // [B]
    const float* __restrict__ pause_budget,  // [B]
    const float* __restrict__ dur_logratio,  // [B,U]
    const float* __restrict__ pause_weight,  // [B,U]
    const float* __restrict__ boundary,      // [B,U]
    const float* __restrict__ phase_ptr,     // [B]
    const float* __restrict__ backlog,       // [B]
    const float* __restrict__ clock_delta,   // [B]
    const int*   __restrict__ commit_front,  // [B]
    const int*   __restrict__ open_run,      // [B,U]
    float* __restrict__ out,                 // f32, 3*B*U + 4*B
    float4* __restrict__ params,             // [B] {visible, sscale, pm, usefb}
    int B) {
  const int wv = threadIdx.x >> 6, ln = threadIdx.x & 63;
  const int row = blockIdx.x * 4 + wv;
  if (row >= B) return;
  const size_t base = (size_t)row * UNITS;

  const int prev = commit_front[row];
  const float sb = speech_budget[row];
  const float pb = pause_budget[row];
  const float pp = phase_ptr[row];
  const float bl = backlog[row];
  const float cd = clock_delta[row];

  // ---- probe visible from prefix mask (2 wave rounds, ~2.3KB/row) ----
  int visible;
  {
    const int i = (ln < 32) ? ln : 0;
    const float v1 = unit_mask[base + 64 * i + 63];
    const int c1 = __popcll(__ballot((ln < 32) && (v1 > 0.5f)));
    if (c1 == 32) {
      visible = 2048;
    } else {
      const int s = 64 * c1;
      const float v2 = unit_mask[base + s + ln];
      visible = s + __popcll(__ballot(v2 > 0.5f));
    }
  }

  // ---- early-exit scan for first open index in [0, visible) ----
  int min_open = INT_MAX;
  for (int cs = 0; cs < visible; cs += 256) {
    const int e = cs + 4 * ln;
    int4 o4 = make_int4(0, 0, 0, 0);
    if (e < visible) o4 = *(const int4*)(open_run + base + e);
    int lm = INT_MAX;
    if (o4.w > 0 && e + 3 < visible) lm = e + 3;
    if (o4.z > 0 && e + 2 < visible) lm = e + 2;
    if (o4.y > 0 && e + 1 < visible) lm = e + 1;
    if (o4.x > 0 && e < visible) lm = e;
    const unsigned long long bb = __ballot(lm != INT_MAX);
    if (bb) {
      min_open = __shfl(lm, (int)__ffsll((unsigned long long)bb) - 1, 64);
      break;
    }
  }

  // ---- ts/tc reduction over the visible prefix only ----
  float sum_sr = 0.f, sum_sc = 0.f;
  for (int cs = 0; cs < visible; cs += 256) {
    const int e = cs + 4 * ln;
    if (e < visible) {
      const float4 a4 = *(const float4*)(dur_anchor   + base + e);
      const float4 l4 = *(const float4*)(dur_logratio + base + e);
      const float4 p4 = *(const float4*)(pause_weight + base + e);
      const float4 b4 = *(const float4*)(boundary     + base + e);
      const float av[4] = {a4.x, a4.y, a4.z, a4.w};
      const float lv[4] = {l4.x, l4.y, l4.z, l4.w};
      const float pv[4] = {p4.x, p4.y, p4.z, p4.w};
      const float bv[4] = {b4.x, b4.y, b4.z, b4.w};
#pragma unroll
      for (int j = 0; j < 4; ++j) {
        const float m = (e + j < visible) ? 1.0f : 0.0f;
        const float a = fmaxf(av[j], 1.0f);                       // MIN_SPEECH_FRAMES
        const float sr = fmaxf(fminf(a * __expf(lv[j]), 3.0f * a), 1.0f) * m;
        const float sc = fmaxf(pv[j], 0.0f) * (0.5f + bv[j]) * m;
        sum_sr += sr;
        sum_sc += sc;
      }
    }
  }
  const float ts = bflySum(sum_sr);
  const float tc = bflySum(sum_sc);
  const float tm = (float)visible;  // sum of prefix mask, exact

  // ---- commit frontier + scales (uniform on all lanes) ----
  const int closed = (min_open == INT_MAX) ? visible : min_open;
  const int relcap = max(visible - 2, 0);             // TAIL_HOLD_UNITS
  int cand = min(relcap, closed);
  const int bidx = min(max(cand - 1, 0), UNITS - 1);
  const float bval = boundary[base + bidx];           // cache-hot
  if (cand > 0 && cand < visible && bval < 0.45f)     // BOUNDARY_COMMIT_THRESHOLD
    cand = max(prev, cand - 1);
  const int commit = max(prev, cand);

  const float sscale = sb / fmaxf(ts, 1e-6f);
  const bool usefb = !(tc > 0.0f);
  const float pscale = pb / fmaxf(tc, 1e-6f);
  const float fbw = pb / fmaxf(tm, 1.0f);
  const float pm = usefb ? fbw : pscale;
  // analytic effective total (linearity)
  const float eff_tot = usefb ? (sscale * ts + fbw * tm) : (sscale * ts + pscale * tc);

  // ---- tiny range sums over [prev,commit) (cache-warm; m==1 inside) ----
  float src_rng = 0.f, eff_rng = 0.f;
  for (int i = prev + ln; i < commit; i += 64) {
    const float a = dur_anchor[base + i];
    const float l = dur_logratio[base + i];
    const float p = pause_weight[base + i];
    const float bo = boundary[base + i];
    src_rng += a;
    const float aa = fmaxf(a, 1.0f);
    const float sr = fmaxf(fminf(aa * __expf(l), 3.0f * aa), 1.0f);
    const float sc = fmaxf(p, 0.0f) * (0.5f + bo);
    eff_rng += sr * sscale + (usefb ? pm : sc * pm);
  }
  const float srcp = bflySum(src_rng);
  const float execp = bflySum(eff_rng);

  if (ln == 0) {
    const bool adv = commit > prev;
    const float nclock = adv ? (cd + (execp - srcp)) : cd;
    const float nback = adv ? fmaxf(nclock, 0.0f) : bl;
    const float vt = fmaxf(eff_tot, 1.0f);
    const float nphase =
        adv ? fminf(fmaxf(pp + execp / vt, 0.0f), 1.0f) : pp;
    const size_t o = 3 * (size_t)B * UNITS;
    out[o + row] = (float)commit;
    out[o + (size_t)B + row] = nphase;
    out[o + 2 * (size_t)B + row] = nback;
    out[o + 3 * (size_t)B + row] = nclock;
    params[row] = make_float4((float)visible, sscale, pm, usefb ? 1.0f : 0.0f);
  }
}

// ---------------- Kernel B: fill-shaped writer ----------------
// One block per half-row (grid 2B). No barriers, no shuffles, no reductions.
__global__ __launch_bounds__(256, 4) void write_kernel(
    const float* __restrict__ dur_anchor,    // [B,U]
    const float* __restrict__ dur_logratio,  // [B,U]
    const float* __restrict__ pause_weight,  // [B,U]
    const float* __restrict__ boundary,      // [B,U]
    const float4* __restrict__ params,       // [B]
    float* __restrict__ out, int B) {
  const int row = blockIdx.x >> 1;           // wave-uniform -> scalar loads
  const int half = blockIdx.x & 1;
  const int e0 = half * 1024 + 4 * threadIdx.x;
  const size_t base = (size_t)row * UNITS;

  const float4 pr = params[row];
  const int visible = (int)pr.x;
  const float sscale = pr.y;
  const float pm = pr.z;
  const bool usefb = pr.w != 0.0f;

  f32x4 s4 = {0.f, 0.f, 0.f, 0.f}, q4 = {0.f, 0.f, 0.f, 0.f},
        e4 = {0.f, 0.f, 0.f, 0.f};
  if (e0 < visible) {
    const float4 a4 = *(const float4*)(dur_anchor   + base + e0);
    const float4 l4 = *(const float4*)(dur_logratio + base + e0);
    const float4 p4 = *(const float4*)(pause_weight + base + e0);
    const float4 b4 = *(const float4*)(boundary     + base + e0);
    const float av[4] = {a4.x, a4.y, a4.z, a4.w};
    const float lv[4] = {l4.x, l4.y, l4.z, l4.w};
    const float pv[4] = {p4.x, p4.y, p4.z, p4.w};
    const float bv[4] = {b4.x, b4.y, b4.z, b4.w};
#pragma unroll
    for (int j = 0; j < 4; ++j) {
      const float m = (e0 + j < visible) ? 1.0f : 0.0f;
      const float a = fmaxf(av[j], 1.0f);                       // MIN_SPEECH_FRAMES
      const float sr = fmaxf(fminf(a * __expf(lv[j]), 3.0f * a), 1.0f);
      const float sc = fmaxf(pv[j], 0.0f) * (0.5f + bv[j]);
      const float speech = sr * sscale * m;
      const float pause = (usefb ? pm : sc * pm) * m;
      s4[j] = speech;
      q4[j] = pause;
      e4[j] = speech + pause;                 // both already masked
    }
  }
  float* __restrict__ out_speech = out;
  float* __restrict__ out_pause  = out + (size_t)B * UNITS;
  float* __restrict__ out_eff    = out + 2 * (size_t)B * UNITS;
  __builtin_nontemporal_store(s4, (f32x4*)(out_speech + base + e0));
  __builtin_nontemporal_store(q4, (f32x4*)(out_pause + base + e0));
  __builtin_nontemporal_store(e4, (f32x4*)(out_eff + base + e0));
}

extern "C" void kernel_launch(void* const* d_in, const int* in_sizes, int n_in,
                              void* d_out, int out_size, void* d_ws, size_t ws_size,
                              hipStream_t stream) {
  const int B = in_sizes[7];  // phase_ptr length
  float4* params = (float4*)d_ws;  // 16 B/row = 64 KB
  stats_kernel<<<dim3((B + 3) / 4), dim3(256), 0, stream>>>(
      (const float*)d_in[0], (const float*)d_in[1], (const float*)d_in[2],
      (const float*)d_in[3], (const float*)d_in[4], (const float*)d_in[5],
      (const float*)d_in[6], (const float*)d_in[7], (const float*)d_in[8],
      (const float*)d_in[9], (const int*)d_in[10], (const int*)d_in[11],
      (float*)d_out, params, B);
  write_kernel<<<dim3(2 * B), dim3(256), 0, stream>>>(
      (const float*)d_in[0], (const float*)d_in[4], (const float*)d_in[5],
      (const float*)d_in[6], params, (float*)d_out, B);
}

// Round 9
// 244.006 us; speedup vs baseline: 1.0339x; 1.0339x over previous
//
#include <hip/hip_runtime.h>
#include <climits>

// StreamingRhythmProjector: B=4096 rows x U=2048 units, one 256-thread block
// (4 waves) per row.
// R9 = R7 (byte-cut: prefix-mask probe, early-exit open scan, predicated
// loads) + critical-path cuts:
//  - barrier 2 DELETED: wave 0 recomputes the tiny [prev,commit) range sums
//    (E[len]~10, L1-hot) after pass-2 stores are issued; in-wave butterfly.
//    Waves 1-3 retire right after their stores (no drain-before-barrier).
//  - __launch_bounds__(256,8): up to 8 resident blocks/CU (VGPR 28 << 64)
//    to interleave per-block latency phases (R7 occupancy was 57%).
//  - pass 2 has no range bookkeeping (fewer VALU between stores).

constexpr int UNITS = 2048;
constexpr int BLOCK = 256;

typedef float f32x4 __attribute__((ext_vector_type(4)));

static __device__ __forceinline__ float waveSum(float v) {
#pragma unroll
  for (int m = 1; m < 64; m <<= 1) v += __shfl_xor(v, m, 64);
  return v;  // all lanes hold the sum
}

__global__ __launch_bounds__(BLOCK, 8) void rhythm_kernel(
    const float* __restrict__ dur_anchor,    // [B,U]
    const float* __restrict__ unit_mask,     // [B,U] prefix mask (0/1)
    const float* __restrict__ speech_budget, // [B]
    const float* __restrict__ pause_budget,  // [B]
    const float* __restrict__ dur_logratio,  // [B,U]
    const float* __restrict__ pause_weight,  // [B,U]
    const float* __restrict__ boundary,      // [B,U]
    const float* __restrict__ phase_ptr,     // [B]
    const float* __restrict__ backlog,       // [B]
    const float* __restrict__ clock_delta,   // [B]
    const int*   __restrict__ commit_front,  // [B]
    const int*   __restrict__ open_run,      // [B,U]
    float* __restrict__ out,                 // f32, 3*B*U + 4*B
    int B) {
  const int row = blockIdx.x;
  const int t = threadIdx.x;
  const int wv = t >> 6, ln = t & 63;
  const size_t base = (size_t)row * UNITS;

  // per-row scalars (wave-uniform s_loads)
  const int prev = commit_front[row];
  const float sb = speech_budget[row];
  const float pb = pause_budget[row];

  // ---- probe `visible` from the prefix mask (~2.3KB instead of 8KB/row) ----
  int visible;
  {
    const int i = (ln < 32) ? ln : 0;
    const float v1 = unit_mask[base + 64 * i + 63];
    const int c1 = __popcll(__ballot((ln < 32) && (v1 > 0.5f)));
    if (c1 == 32) {
      visible = 2048;
    } else {
      const int s = 64 * c1;                       // s <= 1984, s+63 <= 2047
      const float v2 = unit_mask[base + s + ln];
      visible = s + __popcll(__ballot(v2 > 0.5f));
    }
  }

  // ---- early-exit scan for first open index in [0, visible) ----
  int min_open = INT_MAX;
  for (int cs = 0; cs < visible; cs += 256) {
    const int e = cs + 4 * ln;                     // e+3 <= 2047 always
    int4 o4 = make_int4(0, 0, 0, 0);
    if (e < visible) o4 = *(const int4*)(open_run + base + e);
    int lm = INT_MAX;
    if (o4.w > 0 && e + 3 < visible) lm = e + 3;
    if (o4.z > 0 && e + 2 < visible) lm = e + 2;
    if (o4.y > 0 && e + 1 < visible) lm = e + 1;
    if (o4.x > 0 && e < visible) lm = e;
    const unsigned long long bb = __ballot(lm != INT_MAX);
    if (bb) {  // lanes ascend in idx; first set lane holds the chunk min
      min_open = __shfl(lm, (int)__ffsll(bb) - 1, 64);
      break;
    }
  }

  // ---- pass 1: stream 4 arrays over [0, visible) only ----
  float sv_sr[8];  // masked speech_raw
  float sv_sc[8];  // masked pause score
  float sum_sr = 0.f, sum_sc = 0.f;

#pragma unroll
  for (int c = 0; c < 2; ++c) {
    const int e0 = c * 1024 + 4 * t;
    if (e0 < visible) {
      const float4 a4 = *(const float4*)(dur_anchor   + base + e0);
      const float4 l4 = *(const float4*)(dur_logratio + base + e0);
      const float4 p4 = *(const float4*)(pause_weight + base + e0);
      const float4 b4 = *(const float4*)(boundary     + base + e0);
      const float av[4] = {a4.x, a4.y, a4.z, a4.w};
      const float lv[4] = {l4.x, l4.y, l4.z, l4.w};
      const float pv[4] = {p4.x, p4.y, p4.z, p4.w};
      const float bv[4] = {b4.x, b4.y, b4.z, b4.w};
#pragma unroll
      for (int j = 0; j < 4; ++j) {
        const int k = c * 4 + j;
        const float m = (e0 + j < visible) ? 1.0f : 0.0f;
        const float a = fmaxf(av[j], 1.0f);                      // MIN_SPEECH_FRAMES
        const float sr = fmaxf(fminf(a * __expf(lv[j]), 3.0f * a), 1.0f) * m;
        const float sc = fmaxf(pv[j], 0.0f) * (0.5f + bv[j]) * m;
        sv_sr[k] = sr;
        sv_sc[k] = sc;
        sum_sr += sr;
        sum_sc += sc;
      }
    } else {
#pragma unroll
      for (int j = 0; j < 4; ++j) { sv_sr[c * 4 + j] = 0.f; sv_sc[c * 4 + j] = 0.f; }
    }
  }

  // ---- reduction 1 (the ONLY barrier): ts, tc ----
  __shared__ float sf[2][4];
  const float r0 = waveSum(sum_sr);
  const float r1 = waveSum(sum_sc);
  if (ln == 0) { sf[0][wv] = r0; sf[1][wv] = r1; }
  __syncthreads();

  const float ts = sf[0][0] + sf[0][1] + sf[0][2] + sf[0][3];
  const float tc = sf[1][0] + sf[1][1] + sf[1][2] + sf[1][3];
  const float tm = (float)visible;  // sum of prefix mask, exact

  // ---- commit frontier + scales (uniform on all lanes) ----
  const int closed = (min_open == INT_MAX) ? visible : min_open;
  const int relcap = max(visible - 2, 0);             // TAIL_HOLD_UNITS
  int cand = min(relcap, closed);
  const int bidx = min(max(cand - 1, 0), UNITS - 1);
  const float bval = boundary[base + bidx];           // cache-hot
  if (cand > 0 && cand < visible && bval < 0.45f)     // BOUNDARY_COMMIT_THRESHOLD
    cand = max(prev, cand - 1);
  const int commit = max(prev, cand);

  const float sscale = sb / fmaxf(ts, 1e-6f);
  const bool usefb = !(tc > 0.0f);
  const float pscale = pb / fmaxf(tc, 1e-6f);
  const float fbw = pb / fmaxf(tm, 1.0f);
  // analytic effective total (linearity): Sum eff = sscale*ts + pscale*tc
  const float eff_tot = usefb ? (sscale * ts + fbw * tm) : (sscale * ts + pscale * tc);

  // ---- pass 2: pure compute + NT stores, no bookkeeping, no barrier ----
  float* __restrict__ out_speech = out;
  float* __restrict__ out_pause  = out + (size_t)B * UNITS;
  float* __restrict__ out_eff    = out + 2 * (size_t)B * UNITS;

#pragma unroll
  for (int c = 0; c < 2; ++c) {
    const int e0 = c * 1024 + 4 * t;
    f32x4 s4, q4, e4;
#pragma unroll
    for (int j = 0; j < 4; ++j) {
      const int k = c * 4 + j;
      const float m = (e0 + j < visible) ? 1.0f : 0.0f;
      const float speech = sv_sr[k] * sscale;          // sr already masked
      const float pause = usefb ? (m * fbw) : (sv_sc[k] * pscale);
      s4[j] = speech;
      q4[j] = pause;
      e4[j] = speech + pause;                          // both already masked
    }
    __builtin_nontemporal_store(s4, (f32x4*)(out_speech + base + e0));
    __builtin_nontemporal_store(q4, (f32x4*)(out_pause + base + e0));
    __builtin_nontemporal_store(e4, (f32x4*)(out_eff + base + e0));
  }

  // ---- wave 0 alone: tiny [prev,commit) range sums (L1/L2-hot recompute) ----
  if (wv == 0) {
    float src_rng = 0.f, eff_rng = 0.f;
    if (commit > prev) {
      for (int i = prev + ln; i < commit; i += 64) {   // all i < visible here
        const float a = dur_anchor[base + i];
        const float l = dur_logratio[base + i];
        const float p = pause_weight[base + i];
        const float bo = boundary[base + i];
        src_rng += a;
        const float aa = fmaxf(a, 1.0f);
        const float sr = fmaxf(fminf(aa * __expf(l), 3.0f * aa), 1.0f);
        const float sc = fmaxf(p, 0.0f) * (0.5f + bo);
        eff_rng += sr * sscale + (usefb ? fbw : sc * pscale);
      }
    }
    const float srcp = waveSum(src_rng);
    const float execp = waveSum(eff_rng);

    if (ln == 0) {
      const float pp = phase_ptr[row];
      const float bl = backlog[row];
      const float cd = clock_delta[row];
      const bool adv = commit > prev;
      const float nclock = adv ? (cd + (execp - srcp)) : cd;
      const float nback = adv ? fmaxf(nclock, 0.0f) : bl;
      const float vt = fmaxf(eff_tot, 1.0f);
      const float nphase =
          adv ? fminf(fmaxf(pp + execp / vt, 0.0f), 1.0f) : pp;
      const size_t o = 3 * (size_t)B * UNITS;
      out[o + row] = (float)commit;
      out[o + (size_t)B + row] = nphase;
      out[o + 2 * (size_t)B + row] = nback;
      out[o + 3 * (size_t)B + row] = nclock;
    }
  }
}

extern "C" void kernel_launch(void* const* d_in, const int* in_sizes, int n_in,
                              void* d_out, int out_size, void* d_ws, size_t ws_size,
                              hipStream_t stream) {
  const int B = in_sizes[7];  // phase_ptr length
  rhythm_kernel<<<dim3(B), dim3(BLOCK), 0, stream>>>(
      (const float*)d_in[0],   // dur_anchor_src
      (const float*)d_in[1],   // unit_mask
      (const float*)d_in[2],   // speech_budget_win
      (const float*)d_in[3],   // pause_budget_win
      (const float*)d_in[4],   // dur_logratio_unit
      (const float*)d_in[5],   // pause_weight_unit
      (const float*)d_in[6],   // boundary_latent
      (const float*)d_in[7],   // phase_ptr
      (const float*)d_in[8],   // backlog
      (const float*)d_in[9],   // clock_delta
      (const int*)d_in[10],    // commit_frontier
      (const int*)d_in[11],    // open_run_mask
      (float*)d_out, B);
}